// Round 1
// baseline (478.060 us; speedup 1.0000x reference)
//
#include <hip/hip_runtime.h>
#include <math.h>

#define N_ROWS 262144
#define D_IN 64
#define RFF 256
#define GRID_BIG 2048
#define ROWS_PER (N_ROWS / GRID_BIG)   // 128

// d_out layout (floats): predictions[N*3] | AW[N*3] | reg_loss | alpha[256]
#define OFF_PRED 0
#define OFF_AW   (N_ROWS * 3)
#define OFF_REG  (2 * N_ROWS * 3)
#define OFF_ALPHA (2 * N_ROWS * 3 + 1)

// ws layout (floats): U[512] | B[512*3]
#define WS_B 512

// ---------------- Pass 1: column sums U[f] = sum_n Q[n,f] ----------------
__global__ __launch_bounds__(256) void k_colsum(const float* __restrict__ Z,
                                                const float* __restrict__ W,
                                                float* __restrict__ U) {
    const int r = threadIdx.x;  // column 0..255
    float w[D_IN];
#pragma unroll
    for (int d = 0; d < D_IN; ++d) w[d] = W[d * RFF + r];

    const int n0 = blockIdx.x * ROWS_PER;
    float accC = 0.f, accS = 0.f;
    for (int n = n0; n < n0 + ROWS_PER; ++n) {
        const float* __restrict__ z = Z + (size_t)n * D_IN;  // wave-uniform addr
        float p = 0.f;
#pragma unroll
        for (int d = 0; d < D_IN; ++d) p = __builtin_fmaf(z[d], w[d], p);
        float sn, cs;
        __sincosf(p, &sn, &cs);
        accC += cs;
        accS += sn;
    }
    // fold Q scale sqrt(1/256)=1/16 here
    atomicAdd(&U[r], accC * 0.0625f);
    atomicAdd(&U[RFF + r], accS * 0.0625f);
}

// ------------- Tiny kernel: alpha, B = (1/16)*alpha*A, reg_loss -------------
__global__ __launch_bounds__(256) void k_alpha(const float* __restrict__ U,
                                               const float* __restrict__ A,
                                               float* __restrict__ ws,
                                               float* __restrict__ out) {
    __shared__ float sm[256];
    __shared__ float alpha_sh[256];
    __shared__ double gred[256];
    __shared__ double G6[6];
    const int k = threadIdx.x;

    const float am0 = (A[0] + A[1] + A[2]) * (1.0f / 3.0f);
    const float am1 = (A[3] + A[4] + A[5]) * (1.0f / 3.0f);
    float score = (am0 * U[2 * k] + am1 * U[2 * k + 1]) * (1.0f / (float)N_ROWS);
    float x = score * (1.0f / 1.6f);  // / (0.1*sqrt(256))

    // softmax over 256
    sm[k] = x; __syncthreads();
    for (int s = 128; s > 0; s >>= 1) {
        if (k < s) sm[k] = fmaxf(sm[k], sm[k + s]);
        __syncthreads();
    }
    float mx = sm[0]; __syncthreads();
    float e = __expf(x - mx);
    sm[k] = e; __syncthreads();
    for (int s = 128; s > 0; s >>= 1) {
        if (k < s) sm[k] += sm[k + s];
        __syncthreads();
    }
    float al = e / sm[0];
    alpha_sh[k] = al;
    out[OFF_ALPHA + k] = al;
    __syncthreads();

    // B[f][j] = (1/16) * alpha[f>>1] * A[f][j]
    for (int f = k; f < 2 * RFF; f += 256) {
        float a2 = 0.0625f * alpha_sh[f >> 1];
        ws[WS_B + f * 3 + 0] = a2 * A[f * 3 + 0];
        ws[WS_B + f * 3 + 1] = a2 * A[f * 3 + 1];
        ws[WS_B + f * 3 + 2] = a2 * A[f * 3 + 2];
    }

    // --- nuclear norm of A (512x3): G = A^T A in double, closed-form eigs ---
    double af[2][3];
#pragma unroll
    for (int t = 0; t < 2; ++t)
#pragma unroll
        for (int j = 0; j < 3; ++j)
            af[t][j] = (double)A[(k + t * 256) * 3 + j];
    const int ei[6] = {0, 0, 0, 1, 1, 2};
    const int ej[6] = {0, 1, 2, 1, 2, 2};
    for (int eidx = 0; eidx < 6; ++eidx) {
        double p = af[0][ei[eidx]] * af[0][ej[eidx]] + af[1][ei[eidx]] * af[1][ej[eidx]];
        gred[k] = p; __syncthreads();
        for (int s = 128; s > 0; s >>= 1) {
            if (k < s) gred[k] += gred[k + s];
            __syncthreads();
        }
        if (k == 0) G6[eidx] = gred[0];
        __syncthreads();
    }
    if (k == 0) {
        double g00 = G6[0], g01 = G6[1], g02 = G6[2], g11 = G6[3], g12 = G6[4], g22 = G6[5];
        double q = (g00 + g11 + g22) / 3.0;
        double p1 = g01 * g01 + g02 * g02 + g12 * g12;
        double p2 = (g00 - q) * (g00 - q) + (g11 - q) * (g11 - q) + (g22 - q) * (g22 - q) + 2.0 * p1;
        double nuc;
        if (p2 < 1e-300) {
            nuc = 3.0 * sqrt(fmax(q, 0.0));
        } else {
            double p = sqrt(p2 / 6.0);
            double b00 = (g00 - q) / p, b11 = (g11 - q) / p, b22 = (g22 - q) / p;
            double b01 = g01 / p, b02 = g02 / p, b12 = g12 / p;
            double detB = b00 * (b11 * b22 - b12 * b12) - b01 * (b01 * b22 - b12 * b02) +
                          b02 * (b01 * b12 - b11 * b02);
            double rr = detB / 2.0;
            rr = fmin(1.0, fmax(-1.0, rr));
            double phi = acos(rr) / 3.0;
            double e1 = q + 2.0 * p * cos(phi);
            double e3 = q + 2.0 * p * cos(phi + 2.0943951023931953);
            double e2 = 3.0 * q - e1 - e3;
            nuc = sqrt(fmax(e1, 0.0)) + sqrt(fmax(e2, 0.0)) + sqrt(fmax(e3, 0.0));
        }
        out[OFF_REG] = (float)(0.01 * nuc);
    }
}

// ---------------- Pass 2: predictions + AW ----------------
__global__ __launch_bounds__(256) void k_pred(const float* __restrict__ Z,
                                              const float* __restrict__ W,
                                              const float* __restrict__ ws,
                                              float* __restrict__ out) {
    const int r = threadIdx.x;
    const int wv = r >> 6;
    const int lane = r & 63;
    float w[D_IN];
#pragma unroll
    for (int d = 0; d < D_IN; ++d) w[d] = W[d * RFF + r];
    float bc[3], bs[3];
#pragma unroll
    for (int j = 0; j < 3; ++j) {
        bc[j] = ws[WS_B + r * 3 + j];
        bs[j] = ws[WS_B + (RFF + r) * 3 + j];
    }
    __shared__ float part[2][4][3];

    const int n0 = blockIdx.x * ROWS_PER;
    for (int n = n0; n < n0 + ROWS_PER; ++n) {
        const float* __restrict__ z = Z + (size_t)n * D_IN;  // wave-uniform addr
        float p = 0.f;
#pragma unroll
        for (int d = 0; d < D_IN; ++d) p = __builtin_fmaf(z[d], w[d], p);
        float sn, cs;
        __sincosf(p, &sn, &cs);
        float t0 = __builtin_fmaf(cs, bc[0], sn * bs[0]);
        float t1 = __builtin_fmaf(cs, bc[1], sn * bs[1]);
        float t2 = __builtin_fmaf(cs, bc[2], sn * bs[2]);
#pragma unroll
        for (int off = 32; off > 0; off >>= 1) {
            t0 += __shfl_down(t0, off);
            t1 += __shfl_down(t1, off);
            t2 += __shfl_down(t2, off);
        }
        const int buf = n & 1;
        if (lane == 0) {
            part[buf][wv][0] = t0;
            part[buf][wv][1] = t1;
            part[buf][wv][2] = t2;
        }
        __syncthreads();
        if (r < 3) {
            float p0 = part[buf][0][0] + part[buf][1][0] + part[buf][2][0] + part[buf][3][0];
            float p1 = part[buf][0][1] + part[buf][1][1] + part[buf][2][1] + part[buf][3][1];
            float p2 = part[buf][0][2] + part[buf][1][2] + part[buf][2][2] + part[buf][3][2];
            float pj = (r == 0) ? p0 : ((r == 1) ? p1 : p2);
            out[OFF_PRED + (size_t)n * 3 + r] = pj;
            float x0 = p0 * 0.0625f, x1 = p1 * 0.0625f, x2 = p2 * 0.0625f;
            float m = fmaxf(x0, fmaxf(x1, x2));
            float e0 = __expf(x0 - m), e1 = __expf(x1 - m), e2 = __expf(x2 - m);
            float inv = 1.0f / (e0 + e1 + e2);
            float ejv = (r == 0) ? e0 : ((r == 1) ? e1 : e2);
            out[OFF_AW + (size_t)n * 3 + r] = ejv * inv;
        }
    }
}

extern "C" void kernel_launch(void* const* d_in, const int* in_sizes, int n_in,
                              void* d_out, int out_size, void* d_ws, size_t ws_size,
                              hipStream_t stream) {
    const float* Z = (const float*)d_in[0];
    const float* W = (const float*)d_in[1];
    const float* A = (const float*)d_in[2];
    float* out = (float*)d_out;
    float* ws = (float*)d_ws;

    // zero the U accumulators (ws is NOT re-poisoned/zeroed between replays)
    hipMemsetAsync(ws, 0, 512 * sizeof(float), stream);

    hipLaunchKernelGGL(k_colsum, dim3(GRID_BIG), dim3(256), 0, stream, Z, W, ws);
    hipLaunchKernelGGL(k_alpha, dim3(1), dim3(256), 0, stream, ws, A, ws, out);
    hipLaunchKernelGGL(k_pred, dim3(GRID_BIG), dim3(256), 0, stream, Z, W, ws, out);
}

// Round 2
// 426.425 us; speedup vs baseline: 1.1211x; 1.1211x over previous
//
#include <hip/hip_runtime.h>
#include <math.h>

#define N_ROWS 262144
#define D_IN 64
#define RFF 256
#define GRID_BIG 2048
#define ROWS_PER (N_ROWS / GRID_BIG)   // 128

// d_out layout (floats): predictions[N*3] | AW[N*3] | reg_loss | alpha[256]
#define OFF_PRED 0
#define OFF_AW   (N_ROWS * 3)
#define OFF_REG  (2 * N_ROWS * 3)
#define OFF_ALPHA (2 * N_ROWS * 3 + 1)

// ws layout (floats): U[512] | B[512*3]
#define WS_B 512

// ---------------- Pass 1: column sums U[f] = sum_n Q[n,f] ----------------
// thread = feature r; w[:] in VGPRs; z rows are wave-uniform -> s_loads.
// 2 rows in flight x 2 accumulators each = 4 independent FMA chains.
__global__ __launch_bounds__(256) void k_colsum(const float* __restrict__ Z,
                                                const float* __restrict__ W,
                                                float* __restrict__ U) {
    const int r = threadIdx.x;
    float w[D_IN];
#pragma unroll
    for (int d = 0; d < D_IN; ++d) w[d] = W[d * RFF + r];

    const int n0 = blockIdx.x * ROWS_PER;
    float accC = 0.f, accS = 0.f;
    for (int n = n0; n < n0 + ROWS_PER; n += 2) {
        const float* __restrict__ za = Z + (size_t)n * D_IN;  // uniform
        const float* __restrict__ zb = za + D_IN;             // uniform
        float pa0 = 0.f, pa1 = 0.f, pb0 = 0.f, pb1 = 0.f;
#pragma unroll
        for (int d = 0; d < D_IN; d += 2) {
            pa0 = __builtin_fmaf(za[d],     w[d],     pa0);
            pa1 = __builtin_fmaf(za[d + 1], w[d + 1], pa1);
            pb0 = __builtin_fmaf(zb[d],     w[d],     pb0);
            pb1 = __builtin_fmaf(zb[d + 1], w[d + 1], pb1);
        }
        float sa, ca, sb, cb;
        __sincosf(pa0 + pa1, &sa, &ca);
        __sincosf(pb0 + pb1, &sb, &cb);
        accC += ca + cb;
        accS += sa + sb;
    }
    atomicAdd(&U[r], accC * 0.0625f);
    atomicAdd(&U[RFF + r], accS * 0.0625f);
}

// ------------- Tiny kernel: alpha, B = (1/16)*alpha*A, reg_loss -------------
__global__ __launch_bounds__(256) void k_alpha(const float* __restrict__ U,
                                               const float* __restrict__ A,
                                               float* __restrict__ ws,
                                               float* __restrict__ out) {
    __shared__ float sm[256];
    __shared__ float alpha_sh[256];
    __shared__ double gred[256];
    __shared__ double G6[6];
    const int k = threadIdx.x;

    const float am0 = (A[0] + A[1] + A[2]) * (1.0f / 3.0f);
    const float am1 = (A[3] + A[4] + A[5]) * (1.0f / 3.0f);
    float score = (am0 * U[2 * k] + am1 * U[2 * k + 1]) * (1.0f / (float)N_ROWS);
    float x = score * (1.0f / 1.6f);  // / (0.1*sqrt(256))

    sm[k] = x; __syncthreads();
    for (int s = 128; s > 0; s >>= 1) {
        if (k < s) sm[k] = fmaxf(sm[k], sm[k + s]);
        __syncthreads();
    }
    float mx = sm[0]; __syncthreads();
    float e = __expf(x - mx);
    sm[k] = e; __syncthreads();
    for (int s = 128; s > 0; s >>= 1) {
        if (k < s) sm[k] += sm[k + s];
        __syncthreads();
    }
    float al = e / sm[0];
    alpha_sh[k] = al;
    out[OFF_ALPHA + k] = al;
    __syncthreads();

    for (int f = k; f < 2 * RFF; f += 256) {
        float a2 = 0.0625f * alpha_sh[f >> 1];
        ws[WS_B + f * 3 + 0] = a2 * A[f * 3 + 0];
        ws[WS_B + f * 3 + 1] = a2 * A[f * 3 + 1];
        ws[WS_B + f * 3 + 2] = a2 * A[f * 3 + 2];
    }

    // --- nuclear norm of A (512x3): G = A^T A in double, closed-form eigs ---
    double af[2][3];
#pragma unroll
    for (int t = 0; t < 2; ++t)
#pragma unroll
        for (int j = 0; j < 3; ++j)
            af[t][j] = (double)A[(k + t * 256) * 3 + j];
    const int ei[6] = {0, 0, 0, 1, 1, 2};
    const int ej[6] = {0, 1, 2, 1, 2, 2};
    for (int eidx = 0; eidx < 6; ++eidx) {
        double p = af[0][ei[eidx]] * af[0][ej[eidx]] + af[1][ei[eidx]] * af[1][ej[eidx]];
        gred[k] = p; __syncthreads();
        for (int s = 128; s > 0; s >>= 1) {
            if (k < s) gred[k] += gred[k + s];
            __syncthreads();
        }
        if (k == 0) G6[eidx] = gred[0];
        __syncthreads();
    }
    if (k == 0) {
        double g00 = G6[0], g01 = G6[1], g02 = G6[2], g11 = G6[3], g12 = G6[4], g22 = G6[5];
        double q = (g00 + g11 + g22) / 3.0;
        double p1 = g01 * g01 + g02 * g02 + g12 * g12;
        double p2 = (g00 - q) * (g00 - q) + (g11 - q) * (g11 - q) + (g22 - q) * (g22 - q) + 2.0 * p1;
        double nuc;
        if (p2 < 1e-300) {
            nuc = 3.0 * sqrt(fmax(q, 0.0));
        } else {
            double p = sqrt(p2 / 6.0);
            double b00 = (g00 - q) / p, b11 = (g11 - q) / p, b22 = (g22 - q) / p;
            double b01 = g01 / p, b02 = g02 / p, b12 = g12 / p;
            double detB = b00 * (b11 * b22 - b12 * b12) - b01 * (b01 * b22 - b12 * b02) +
                          b02 * (b01 * b12 - b11 * b02);
            double rr = detB / 2.0;
            rr = fmin(1.0, fmax(-1.0, rr));
            double phi = acos(rr) / 3.0;
            double e1 = q + 2.0 * p * cos(phi);
            double e3 = q + 2.0 * p * cos(phi + 2.0943951023931953);
            double e2 = 3.0 * q - e1 - e3;
            nuc = sqrt(fmax(e1, 0.0)) + sqrt(fmax(e2, 0.0)) + sqrt(fmax(e3, 0.0));
        }
        out[OFF_REG] = (float)(0.01 * nuc);
    }
}

// ---------------- Pass 2: predictions + AW ----------------
// 4 rows per reduction round; LDS-batched reduction replaces per-row butterfly.
__global__ __launch_bounds__(256) void k_pred(const float* __restrict__ Z,
                                              const float* __restrict__ W,
                                              const float* __restrict__ ws,
                                              float* __restrict__ out) {
    const int r = threadIdx.x;
    float w[D_IN];
#pragma unroll
    for (int d = 0; d < D_IN; ++d) w[d] = W[d * RFF + r];
    float bc[3], bs[3];
#pragma unroll
    for (int j = 0; j < 3; ++j) {
        bc[j] = ws[WS_B + r * 3 + j];
        bs[j] = ws[WS_B + (RFF + r) * 3 + j];
    }
    // red[pair][t]: pair = row*3+j (12 used), 272 stride -> 2-way banks (free)
    __shared__ float red[12][272];
    __shared__ float fin[12];

    const int pair = r >> 4;  // 0..15, use 0..11
    const int seg  = r & 15;

    const int n0 = blockIdx.x * ROWS_PER;
    for (int n = n0; n < n0 + ROWS_PER; n += 4) {
        float t[4][3];
#pragma unroll
        for (int rr = 0; rr < 4; rr += 2) {
            const float* __restrict__ za = Z + (size_t)(n + rr) * D_IN;  // uniform
            const float* __restrict__ zb = za + D_IN;                    // uniform
            float pa0 = 0.f, pa1 = 0.f, pb0 = 0.f, pb1 = 0.f;
#pragma unroll
            for (int d = 0; d < D_IN; d += 2) {
                pa0 = __builtin_fmaf(za[d],     w[d],     pa0);
                pa1 = __builtin_fmaf(za[d + 1], w[d + 1], pa1);
                pb0 = __builtin_fmaf(zb[d],     w[d],     pb0);
                pb1 = __builtin_fmaf(zb[d + 1], w[d + 1], pb1);
            }
            float sa, ca, sb, cb;
            __sincosf(pa0 + pa1, &sa, &ca);
            __sincosf(pb0 + pb1, &sb, &cb);
#pragma unroll
            for (int j = 0; j < 3; ++j) {
                t[rr][j]     = __builtin_fmaf(ca, bc[j], sa * bs[j]);
                t[rr + 1][j] = __builtin_fmaf(cb, bc[j], sb * bs[j]);
            }
        }
#pragma unroll
        for (int p = 0; p < 12; ++p) red[p][r] = t[p / 3][p % 3];
        __syncthreads();
        if (r < 192) {
            float s = 0.f;
#pragma unroll
            for (int i = 0; i < 16; ++i) s += red[pair][i * 16 + seg];
#pragma unroll
            for (int off = 8; off > 0; off >>= 1) s += __shfl_down(s, off, 16);
            if (seg == 0) {
                const int row = pair / 3, j = pair % 3;
                out[OFF_PRED + (size_t)(n + row) * 3 + j] = s;
                fin[pair] = s;
            }
        }
        __syncthreads();
        if (r < 4) {
            float x0 = fin[r * 3 + 0] * 0.0625f;
            float x1 = fin[r * 3 + 1] * 0.0625f;
            float x2 = fin[r * 3 + 2] * 0.0625f;
            float m = fmaxf(x0, fmaxf(x1, x2));
            float e0 = __expf(x0 - m), e1 = __expf(x1 - m), e2 = __expf(x2 - m);
            float inv = 1.0f / (e0 + e1 + e2);
            out[OFF_AW + (size_t)(n + r) * 3 + 0] = e0 * inv;
            out[OFF_AW + (size_t)(n + r) * 3 + 1] = e1 * inv;
            out[OFF_AW + (size_t)(n + r) * 3 + 2] = e2 * inv;
        }
        // next-iter red writes happen after the sync above -> no extra sync needed
    }
}

extern "C" void kernel_launch(void* const* d_in, const int* in_sizes, int n_in,
                              void* d_out, int out_size, void* d_ws, size_t ws_size,
                              hipStream_t stream) {
    const float* Z = (const float*)d_in[0];
    const float* W = (const float*)d_in[1];
    const float* A = (const float*)d_in[2];
    float* out = (float*)d_out;
    float* ws = (float*)d_ws;

    hipMemsetAsync(ws, 0, 512 * sizeof(float), stream);
    hipLaunchKernelGGL(k_colsum, dim3(GRID_BIG), dim3(256), 0, stream, Z, W, ws);
    hipLaunchKernelGGL(k_alpha, dim3(1), dim3(256), 0, stream, ws, A, ws, out);
    hipLaunchKernelGGL(k_pred, dim3(GRID_BIG), dim3(256), 0, stream, Z, W, ws, out);
}

// Round 3
// 355.426 us; speedup vs baseline: 1.3450x; 1.1998x over previous
//
#include <hip/hip_runtime.h>
#include <math.h>

#define N_ROWS 262144
#define D_IN 64
#define RFF 256
#define NTILES (N_ROWS / 16)                 // 16384
#define GRID_BIG 1024
#define TILES_PER_BLOCK (NTILES / GRID_BIG)  // 16
#define TILES_PER_WAVE (TILES_PER_BLOCK / 4) // 4

// d_out layout (floats): predictions[N*3] | AW[N*3] | reg_loss | alpha[256]
#define OFF_PRED 0
#define OFF_AW (N_ROWS * 3)
#define OFF_REG (2 * N_ROWS * 3)
#define OFF_ALPHA (2 * N_ROWS * 3 + 1)

// ws layout (floats): U[512] | B[512*3]
#define WS_B 512

typedef _Float16 f16x8 __attribute__((ext_vector_type(8)));
typedef float f32x4 __attribute__((ext_vector_type(4)));

__device__ __forceinline__ f32x4 mfma16(f16x8 a, f16x8 b, f32x4 c) {
    return __builtin_amdgcn_mfma_f32_16x16x32_f16(a, b, c, 0, 0, 0);
}

// Stage W (64x256 f32) into LDS as f16 B-fragments.
// Frag layout for v_mfma_f32_16x16x32_f16 B-operand: lane l, elem i ->
//   k = kh*32 + 8*(l>>4) + i, col = ct*16 + (l&15).
// LDS slot index: (ct*2 + kh)*64 + lane.
__device__ __forceinline__ void prep_W(const float* __restrict__ W, f16x8* Bf, int t) {
#pragma unroll
    for (int q = 0; q < 8; ++q) {
        const int s = t + 256 * q;
        const int lane = s & 63;
        const int kh = (s >> 6) & 1;
        const int ct = s >> 7;
        const int k0 = kh * 32 + 8 * (lane >> 4);
        const int col = ct * 16 + (lane & 15);
        f16x8 v;
#pragma unroll
        for (int i = 0; i < 8; ++i) v[i] = (_Float16)W[(k0 + i) * RFF + col];
        Bf[(ct * 2 + kh) * 64 + lane] = v;
    }
}

// Load one 16x64 Z tile into A-fragments (f16 hi + f16 residual lo).
// A layout: lane l, elem i -> row = l&15, k = kh*32 + 8*(l>>4) + i.
__device__ __forceinline__ void load_A(const float* __restrict__ Z, int n0, int lr, int lh,
                                       f16x8& ah0, f16x8& al0, f16x8& ah1, f16x8& al1) {
    const float* zr = Z + (size_t)(n0 + lr) * D_IN + lh * 8;
    float z[16];
    *(float4*)&z[0] = *(const float4*)(zr);
    *(float4*)&z[4] = *(const float4*)(zr + 4);
    *(float4*)&z[8] = *(const float4*)(zr + 32);
    *(float4*)&z[12] = *(const float4*)(zr + 36);
#pragma unroll
    for (int i = 0; i < 8; ++i) {
        _Float16 h0 = (_Float16)z[i];
        ah0[i] = h0;
        al0[i] = (_Float16)(z[i] - (float)h0);
        _Float16 h1 = (_Float16)z[8 + i];
        ah1[i] = h1;
        al1[i] = (_Float16)(z[8 + i] - (float)h1);
    }
}

// ---------------- Pass 1: U[f] = sum_n Q[n,f] via MFMA ----------------
__global__ __launch_bounds__(256, 3) void k_pass1(const float* __restrict__ Z,
                                                  const float* __restrict__ W,
                                                  float* __restrict__ U) {
    __shared__ f16x8 Bf[2048];     // 32 KB
    __shared__ float Ured[512];
    const int t = threadIdx.x;
    prep_W(W, Bf, t);
    Ured[t] = 0.f;
    Ured[t + 256] = 0.f;
    __syncthreads();

    const int wv = t >> 6, l = t & 63, lr = l & 15, lh = l >> 4;
    float accC[16], accS[16];
#pragma unroll
    for (int c = 0; c < 16; ++c) { accC[c] = 0.f; accS[c] = 0.f; }

    for (int tt = 0; tt < TILES_PER_WAVE; ++tt) {
        const int tile = blockIdx.x * TILES_PER_BLOCK + wv * TILES_PER_WAVE + tt;
        const int n0 = tile * 16;
        f16x8 ah0, al0, ah1, al1;
        load_A(Z, n0, lr, lh, ah0, al0, ah1, al1);
        f32x4 acc[16];
#pragma unroll
        for (int ct = 0; ct < 16; ++ct) acc[ct] = (f32x4){0.f, 0.f, 0.f, 0.f};
#pragma unroll
        for (int ct = 0; ct < 16; ++ct) {
            f16x8 b0 = Bf[(ct * 2 + 0) * 64 + l];
            f16x8 b1 = Bf[(ct * 2 + 1) * 64 + l];
            acc[ct] = mfma16(ah0, b0, acc[ct]);
            acc[ct] = mfma16(ah1, b1, acc[ct]);
            acc[ct] = mfma16(al0, b0, acc[ct]);
            acc[ct] = mfma16(al1, b1, acc[ct]);
        }
#pragma unroll
        for (int ct = 0; ct < 16; ++ct) {
#pragma unroll
            for (int r = 0; r < 4; ++r) {
                float sn, cs;
                __sincosf(acc[ct][r], &sn, &cs);
                accC[ct] += cs;
                accS[ct] += sn;
            }
        }
    }
    // reduce across the 4 row-groups (lanes sharing l&15): xor 16, 32
#pragma unroll
    for (int ct = 0; ct < 16; ++ct) {
        accC[ct] += __shfl_xor(accC[ct], 16);
        accC[ct] += __shfl_xor(accC[ct], 32);
        accS[ct] += __shfl_xor(accS[ct], 16);
        accS[ct] += __shfl_xor(accS[ct], 32);
    }
    if (l < 16) {
#pragma unroll
        for (int ct = 0; ct < 16; ++ct) {
            atomicAdd(&Ured[ct * 16 + l], accC[ct] * 0.0625f);
            atomicAdd(&Ured[256 + ct * 16 + l], accS[ct] * 0.0625f);
        }
    }
    __syncthreads();
    atomicAdd(&U[t], Ured[t]);
    atomicAdd(&U[t + 256], Ured[t + 256]);
}

// ------------- Tiny kernel: alpha, B = (1/16)*alpha*A, reg_loss -------------
__global__ __launch_bounds__(256) void k_alpha(const float* __restrict__ U,
                                               const float* __restrict__ A,
                                               float* __restrict__ ws,
                                               float* __restrict__ out) {
    __shared__ float sm[256];
    __shared__ float alpha_sh[256];
    __shared__ double gred[256];
    __shared__ double G6[6];
    const int k = threadIdx.x;

    const float am0 = (A[0] + A[1] + A[2]) * (1.0f / 3.0f);
    const float am1 = (A[3] + A[4] + A[5]) * (1.0f / 3.0f);
    float score = (am0 * U[2 * k] + am1 * U[2 * k + 1]) * (1.0f / (float)N_ROWS);
    float x = score * (1.0f / 1.6f);

    sm[k] = x;
    __syncthreads();
    for (int s = 128; s > 0; s >>= 1) {
        if (k < s) sm[k] = fmaxf(sm[k], sm[k + s]);
        __syncthreads();
    }
    float mx = sm[0];
    __syncthreads();
    float e = __expf(x - mx);
    sm[k] = e;
    __syncthreads();
    for (int s = 128; s > 0; s >>= 1) {
        if (k < s) sm[k] += sm[k + s];
        __syncthreads();
    }
    float al = e / sm[0];
    alpha_sh[k] = al;
    out[OFF_ALPHA + k] = al;
    __syncthreads();

    for (int f = k; f < 2 * RFF; f += 256) {
        float a2 = 0.0625f * alpha_sh[f >> 1];
        ws[WS_B + f * 3 + 0] = a2 * A[f * 3 + 0];
        ws[WS_B + f * 3 + 1] = a2 * A[f * 3 + 1];
        ws[WS_B + f * 3 + 2] = a2 * A[f * 3 + 2];
    }

    // nuclear norm of A (512x3): G = A^T A in double, closed-form eigs
    double af[2][3];
#pragma unroll
    for (int t2 = 0; t2 < 2; ++t2)
#pragma unroll
        for (int j = 0; j < 3; ++j) af[t2][j] = (double)A[(k + t2 * 256) * 3 + j];
    const int ei[6] = {0, 0, 0, 1, 1, 2};
    const int ej[6] = {0, 1, 2, 1, 2, 2};
    for (int eidx = 0; eidx < 6; ++eidx) {
        double p = af[0][ei[eidx]] * af[0][ej[eidx]] + af[1][ei[eidx]] * af[1][ej[eidx]];
        gred[k] = p;
        __syncthreads();
        for (int s = 128; s > 0; s >>= 1) {
            if (k < s) gred[k] += gred[k + s];
            __syncthreads();
        }
        if (k == 0) G6[eidx] = gred[0];
        __syncthreads();
    }
    if (k == 0) {
        double g00 = G6[0], g01 = G6[1], g02 = G6[2], g11 = G6[3], g12 = G6[4], g22 = G6[5];
        double q = (g00 + g11 + g22) / 3.0;
        double p1 = g01 * g01 + g02 * g02 + g12 * g12;
        double p2 = (g00 - q) * (g00 - q) + (g11 - q) * (g11 - q) + (g22 - q) * (g22 - q) + 2.0 * p1;
        double nuc;
        if (p2 < 1e-300) {
            nuc = 3.0 * sqrt(fmax(q, 0.0));
        } else {
            double p = sqrt(p2 / 6.0);
            double b00 = (g00 - q) / p, b11 = (g11 - q) / p, b22 = (g22 - q) / p;
            double b01 = g01 / p, b02 = g02 / p, b12 = g12 / p;
            double detB = b00 * (b11 * b22 - b12 * b12) - b01 * (b01 * b22 - b12 * b02) +
                          b02 * (b01 * b12 - b11 * b02);
            double rr = detB / 2.0;
            rr = fmin(1.0, fmax(-1.0, rr));
            double phi = acos(rr) / 3.0;
            double e1 = q + 2.0 * p * cos(phi);
            double e3 = q + 2.0 * p * cos(phi + 2.0943951023931953);
            double e2 = 3.0 * q - e1 - e3;
            nuc = sqrt(fmax(e1, 0.0)) + sqrt(fmax(e2, 0.0)) + sqrt(fmax(e3, 0.0));
        }
        out[OFF_REG] = (float)(0.01 * nuc);
    }
}

// ---------------- Pass 2: predictions + AW via MFMA ----------------
__global__ __launch_bounds__(256, 3) void k_pass2(const float* __restrict__ Z,
                                                  const float* __restrict__ W,
                                                  const float* __restrict__ ws,
                                                  float* __restrict__ out) {
    __shared__ f16x8 Bf[2048];     // 32 KB
    __shared__ float BtA[256 * 4]; // bc0,bc1,bc2,bs0 per feature
    __shared__ float BtB[256 * 2]; // bs1,bs2 per feature
    const int t = threadIdx.x;
    prep_W(W, Bf, t);
    {
        const float* Bt = ws + WS_B;
        BtA[t * 4 + 0] = Bt[t * 3 + 0];
        BtA[t * 4 + 1] = Bt[t * 3 + 1];
        BtA[t * 4 + 2] = Bt[t * 3 + 2];
        BtA[t * 4 + 3] = Bt[(256 + t) * 3 + 0];
        BtB[t * 2 + 0] = Bt[(256 + t) * 3 + 1];
        BtB[t * 2 + 1] = Bt[(256 + t) * 3 + 2];
    }
    __syncthreads();

    const int wv = t >> 6, l = t & 63, lr = l & 15, lh = l >> 4;

    for (int tt = 0; tt < TILES_PER_WAVE; ++tt) {
        const int tile = blockIdx.x * TILES_PER_BLOCK + wv * TILES_PER_WAVE + tt;
        const int n0 = tile * 16;
        f16x8 ah0, al0, ah1, al1;
        load_A(Z, n0, lr, lh, ah0, al0, ah1, al1);
        f32x4 acc[16];
#pragma unroll
        for (int ct = 0; ct < 16; ++ct) acc[ct] = (f32x4){0.f, 0.f, 0.f, 0.f};
#pragma unroll
        for (int ct = 0; ct < 16; ++ct) {
            f16x8 b0 = Bf[(ct * 2 + 0) * 64 + l];
            f16x8 b1 = Bf[(ct * 2 + 1) * 64 + l];
            acc[ct] = mfma16(ah0, b0, acc[ct]);
            acc[ct] = mfma16(ah1, b1, acc[ct]);
            acc[ct] = mfma16(al0, b0, acc[ct]);
            acc[ct] = mfma16(al1, b1, acc[ct]);
        }
        float pa[4][3];
#pragma unroll
        for (int r = 0; r < 4; ++r) { pa[r][0] = 0.f; pa[r][1] = 0.f; pa[r][2] = 0.f; }
#pragma unroll
        for (int ct = 0; ct < 16; ++ct) {
            const int f = ct * 16 + lr;
            float4 bA = *(const float4*)&BtA[f * 4];
            float bs1 = BtB[f * 2 + 0], bs2 = BtB[f * 2 + 1];
#pragma unroll
            for (int r = 0; r < 4; ++r) {
                float sn, cs;
                __sincosf(acc[ct][r], &sn, &cs);
                pa[r][0] = __builtin_fmaf(cs, bA.x, __builtin_fmaf(sn, bA.w, pa[r][0]));
                pa[r][1] = __builtin_fmaf(cs, bA.y, __builtin_fmaf(sn, bs1, pa[r][1]));
                pa[r][2] = __builtin_fmaf(cs, bA.z, __builtin_fmaf(sn, bs2, pa[r][2]));
            }
        }
        // reduce over the 16 lanes (cols) sharing the same rows
#pragma unroll
        for (int r = 0; r < 4; ++r)
#pragma unroll
            for (int j = 0; j < 3; ++j) {
                pa[r][j] += __shfl_xor(pa[r][j], 1);
                pa[r][j] += __shfl_xor(pa[r][j], 2);
                pa[r][j] += __shfl_xor(pa[r][j], 4);
                pa[r][j] += __shfl_xor(pa[r][j], 8);
            }
        // lane lr<4 owns row n0 + 4*lh + lr (static-indexed select, rule #20)
        float q0 = 0.f, q1 = 0.f, q2 = 0.f;
#pragma unroll
        for (int r = 0; r < 4; ++r)
            if (lr == r) { q0 = pa[r][0]; q1 = pa[r][1]; q2 = pa[r][2]; }
        if (lr < 4) {
            const size_t n = (size_t)n0 + 4 * lh + lr;
            out[OFF_PRED + n * 3 + 0] = q0;
            out[OFF_PRED + n * 3 + 1] = q1;
            out[OFF_PRED + n * 3 + 2] = q2;
            float x0 = q0 * 0.0625f, x1 = q1 * 0.0625f, x2 = q2 * 0.0625f;
            float m = fmaxf(x0, fmaxf(x1, x2));
            float e0 = __expf(x0 - m), e1 = __expf(x1 - m), e2 = __expf(x2 - m);
            float inv = 1.0f / (e0 + e1 + e2);
            out[OFF_AW + n * 3 + 0] = e0 * inv;
            out[OFF_AW + n * 3 + 1] = e1 * inv;
            out[OFF_AW + n * 3 + 2] = e2 * inv;
        }
    }
}

extern "C" void kernel_launch(void* const* d_in, const int* in_sizes, int n_in,
                              void* d_out, int out_size, void* d_ws, size_t ws_size,
                              hipStream_t stream) {
    const float* Z = (const float*)d_in[0];
    const float* W = (const float*)d_in[1];
    const float* A = (const float*)d_in[2];
    float* out = (float*)d_out;
    float* ws = (float*)d_ws;

    hipMemsetAsync(ws, 0, 512 * sizeof(float), stream);
    hipLaunchKernelGGL(k_pass1, dim3(GRID_BIG), dim3(256), 0, stream, Z, W, ws);
    hipLaunchKernelGGL(k_alpha, dim3(1), dim3(256), 0, stream, ws, A, ws, out);
    hipLaunchKernelGGL(k_pass2, dim3(GRID_BIG), dim3(256), 0, stream, Z, W, ws, out);
}

// Round 5
// 100.503 us; speedup vs baseline: 4.7567x; 3.5365x over previous
//
#include <hip/hip_runtime.h>
#include <math.h>

#define N_ROWS 262144
#define D_IN 64
#define RFF 256
#define NTILES (N_ROWS / 16)                 // 16384
#define GRID_BIG 512
#define TILES_PER_BLOCK (NTILES / GRID_BIG)  // 32
#define TILES_PER_WAVE (TILES_PER_BLOCK / 4) // 8

// d_out layout (floats): predictions[N*3] | AW[N*3] | reg_loss | alpha[256]
#define OFF_PRED 0
#define OFF_AW (N_ROWS * 3)
#define OFF_REG (2 * N_ROWS * 3)
#define OFF_ALPHA (2 * N_ROWS * 3 + 1)

// ws layout: U f32[512] | BtP u32[256*3] (packed bf16: lo=cos-coef, hi=sin-coef)
#define WS_B 512

typedef _Float16 f16x8 __attribute__((ext_vector_type(8)));
typedef float f32x4 __attribute__((ext_vector_type(4)));

__device__ __forceinline__ f32x4 mfma16(f16x8 a, f16x8 b, f32x4 c) {
    return __builtin_amdgcn_mfma_f32_16x16x32_f16(a, b, c, 0, 0, 0);
}

__device__ __forceinline__ unsigned short f32_to_bf16_rne(float x) {
    unsigned int u = __float_as_uint(x);
    unsigned int r = u + 0x7fffu + ((u >> 16) & 1u);
    return (unsigned short)(r >> 16);
}

// Stage W (64x256 f32) into LDS as f16 B-fragments.
// B-frag layout (v_mfma_f32_16x16x32_f16): lane l, elem i ->
//   k = kh*32 + 8*(l>>4) + i, col = ct*16 + (l&15).  slot = (ct*2+kh)*64 + l.
__device__ __forceinline__ void prep_W(const float* __restrict__ W, f16x8* Bf, int t) {
#pragma unroll
    for (int q = 0; q < 8; ++q) {
        const int s = t + 256 * q;
        const int lane = s & 63;
        const int kh = (s >> 6) & 1;
        const int ct = s >> 7;
        const int k0 = kh * 32 + 8 * (lane >> 4);
        const int col = ct * 16 + (lane & 15);
        f16x8 v;
#pragma unroll
        for (int i = 0; i < 8; ++i) v[i] = (_Float16)W[(k0 + i) * RFF + col];
        Bf[(ct * 2 + kh) * 64 + lane] = v;
    }
}

// Coalesced global -> LDS stage of one 16x64 f32 Z tile (per wave).
// Each instr covers 8 full rows x 128B lines; LDS row stride 68 floats.
__device__ __forceinline__ void stage_Z(const float* __restrict__ Z, int n0,
                                        float (*Zw)[68], int l) {
#pragma unroll
    for (int rep = 0; rep < 4; ++rep) {
        const int row = (rep >> 1) * 8 + (l >> 3);
        const int col = (rep & 1) * 32 + (l & 7) * 4;
        const float4 v = *(const float4*)(Z + (size_t)(n0 + row) * D_IN + col);
        *(float4*)&Zw[row][col] = v;
    }
    asm volatile("s_waitcnt lgkmcnt(0)" ::: "memory");
}

// Read this lane's A-fragments (f16 hi + f16 residual lo) from the staged tile.
__device__ __forceinline__ void frags_from_lds(const float (*Zw)[68], int lr, int lh,
                                               f16x8& ah0, f16x8& al0, f16x8& ah1, f16x8& al1) {
    const float* zr = &Zw[lr][lh * 8];
    float z[16];
    *(float4*)&z[0] = *(const float4*)(zr);
    *(float4*)&z[4] = *(const float4*)(zr + 4);
    *(float4*)&z[8] = *(const float4*)(zr + 32);
    *(float4*)&z[12] = *(const float4*)(zr + 36);
#pragma unroll
    for (int i = 0; i < 8; ++i) {
        _Float16 h0 = (_Float16)z[i];
        ah0[i] = h0;
        al0[i] = (_Float16)(z[i] - (float)h0);
        _Float16 h1 = (_Float16)z[8 + i];
        ah1[i] = h1;
        al1[i] = (_Float16)(z[8 + i] - (float)h1);
    }
}

// ---------------- Pass 1: U[f] = sum_n Q[n,f] via MFMA ----------------
__global__ __launch_bounds__(256, 3) void k_pass1(const float* __restrict__ Z,
                                                  const float* __restrict__ W,
                                                  float* __restrict__ U) {
    __shared__ f16x8 Bf[2048];       // 32 KB
    __shared__ float Zs[4][16][68];  // 17.4 KB
    __shared__ float Ured[512];
    const int t = threadIdx.x;
    prep_W(W, Bf, t);
    Ured[t] = 0.f;
    Ured[t + 256] = 0.f;
    __syncthreads();

    const int wv = t >> 6, l = t & 63, lr = l & 15, lh = l >> 4;
    float accC[16], accS[16];
#pragma unroll
    for (int c = 0; c < 16; ++c) { accC[c] = 0.f; accS[c] = 0.f; }

    for (int tt = 0; tt < TILES_PER_WAVE; ++tt) {
        const int tile = blockIdx.x * TILES_PER_BLOCK + wv * TILES_PER_WAVE + tt;
        const int n0 = tile * 16;
        stage_Z(Z, n0, Zs[wv], l);
        f16x8 ah0, al0, ah1, al1;
        frags_from_lds(Zs[wv], lr, lh, ah0, al0, ah1, al1);
        f32x4 acc[16];
#pragma unroll
        for (int ct = 0; ct < 16; ++ct) acc[ct] = (f32x4){0.f, 0.f, 0.f, 0.f};
#pragma unroll
        for (int ct = 0; ct < 16; ++ct) {
            f16x8 b0 = Bf[(ct * 2 + 0) * 64 + l];
            f16x8 b1 = Bf[(ct * 2 + 1) * 64 + l];
            acc[ct] = mfma16(ah0, b0, acc[ct]);
            acc[ct] = mfma16(ah1, b1, acc[ct]);
            acc[ct] = mfma16(al0, b0, acc[ct]);
            acc[ct] = mfma16(al1, b1, acc[ct]);
        }
#pragma unroll
        for (int ct = 0; ct < 16; ++ct) {
#pragma unroll
            for (int r = 0; r < 4; ++r) {
                float sn, cs;
                __sincosf(acc[ct][r], &sn, &cs);
                accC[ct] += cs;
                accS[ct] += sn;
            }
        }
    }
#pragma unroll
    for (int ct = 0; ct < 16; ++ct) {
        accC[ct] += __shfl_xor(accC[ct], 16);
        accC[ct] += __shfl_xor(accC[ct], 32);
        accS[ct] += __shfl_xor(accS[ct], 16);
        accS[ct] += __shfl_xor(accS[ct], 32);
    }
    if (l < 16) {
#pragma unroll
        for (int ct = 0; ct < 16; ++ct) {
            atomicAdd(&Ured[ct * 16 + l], accC[ct] * 0.0625f);
            atomicAdd(&Ured[256 + ct * 16 + l], accS[ct] * 0.0625f);
        }
    }
    __syncthreads();
    atomicAdd(&U[t], Ured[t]);
    atomicAdd(&U[t + 256], Ured[t + 256]);
}

// ------------- Tiny kernel: alpha, packed B coefs, reg_loss -------------
__global__ __launch_bounds__(256) void k_alpha(const float* __restrict__ U,
                                               const float* __restrict__ A,
                                               float* __restrict__ ws,
                                               float* __restrict__ out) {
    __shared__ float sm[256];
    __shared__ double gred[256];
    __shared__ double G6[6];
    const int k = threadIdx.x;

    const float am0 = (A[0] + A[1] + A[2]) * (1.0f / 3.0f);
    const float am1 = (A[3] + A[4] + A[5]) * (1.0f / 3.0f);
    float score = (am0 * U[2 * k] + am1 * U[2 * k + 1]) * (1.0f / (float)N_ROWS);
    float x = score * (1.0f / 1.6f);

    sm[k] = x;
    __syncthreads();
    for (int s = 128; s > 0; s >>= 1) {
        if (k < s) sm[k] = fmaxf(sm[k], sm[k + s]);
        __syncthreads();
    }
    float mx = sm[0];
    __syncthreads();
    float e = __expf(x - mx);
    sm[k] = e;
    __syncthreads();
    for (int s = 128; s > 0; s >>= 1) {
        if (k < s) sm[k] += sm[k + s];
        __syncthreads();
    }
    float al = e / sm[0];
    out[OFF_ALPHA + k] = al;
    sm[k] = al;
    __syncthreads();

    // packed B coefs for col k: lo bf16 = (1/16)*alpha[k>>1]*A[k][j],
    //                           hi bf16 = (1/16)*alpha[128+(k>>1)]*A[256+k][j]
    {
        const float ac = 0.0625f * sm[k >> 1];
        const float as = 0.0625f * sm[128 + (k >> 1)];
        unsigned int* BtP = (unsigned int*)(ws + WS_B);
#pragma unroll
        for (int j = 0; j < 3; ++j) {
            float bc = ac * A[k * 3 + j];
            float bs = as * A[(256 + k) * 3 + j];
            unsigned int ulo = f32_to_bf16_rne(bc);
            unsigned int uhi = f32_to_bf16_rne(bs);
            BtP[k * 3 + j] = ulo | (uhi << 16);
        }
    }

    // nuclear norm of A (512x3): G = A^T A in double, closed-form eigs
    double af[2][3];
#pragma unroll
    for (int t2 = 0; t2 < 2; ++t2)
#pragma unroll
        for (int j = 0; j < 3; ++j) af[t2][j] = (double)A[(k + t2 * 256) * 3 + j];
    const int ei[6] = {0, 0, 0, 1, 1, 2};
    const int ej[6] = {0, 1, 2, 1, 2, 2};
    for (int eidx = 0; eidx < 6; ++eidx) {
        double p = af[0][ei[eidx]] * af[0][ej[eidx]] + af[1][ei[eidx]] * af[1][ej[eidx]];
        gred[k] = p;
        __syncthreads();
        for (int s = 128; s > 0; s >>= 1) {
            if (k < s) gred[k] += gred[k + s];
            __syncthreads();
        }
        if (k == 0) G6[eidx] = gred[0];
        __syncthreads();
    }
    if (k == 0) {
        double g00 = G6[0], g01 = G6[1], g02 = G6[2], g11 = G6[3], g12 = G6[4], g22 = G6[5];
        double q = (g00 + g11 + g22) / 3.0;
        double p1 = g01 * g01 + g02 * g02 + g12 * g12;
        double p2 = (g00 - q) * (g00 - q) + (g11 - q) * (g11 - q) + (g22 - q) * (g22 - q) + 2.0 * p1;
        double nuc;
        if (p2 < 1e-300) {
            nuc = 3.0 * sqrt(fmax(q, 0.0));
        } else {
            double p = sqrt(p2 / 6.0);
            double b00 = (g00 - q) / p, b11 = (g11 - q) / p, b22 = (g22 - q) / p;
            double b01 = g01 / p, b02 = g02 / p, b12 = g12 / p;
            double detB = b00 * (b11 * b22 - b12 * b12) - b01 * (b01 * b22 - b12 * b02) +
                          b02 * (b01 * b12 - b11 * b02);
            double rr = detB / 2.0;
            rr = fmin(1.0, fmax(-1.0, rr));
            double phi = acos(rr) / 3.0;
            double e1 = q + 2.0 * p * cos(phi);
            double e3 = q + 2.0 * p * cos(phi + 2.0943951023931953);
            double e2 = 3.0 * q - e1 - e3;
            nuc = sqrt(fmax(e1, 0.0)) + sqrt(fmax(e2, 0.0)) + sqrt(fmax(e3, 0.0));
        }
        out[OFF_REG] = (float)(0.01 * nuc);
    }
}

// ---------------- Pass 2: predictions + AW via MFMA ----------------
__global__ __launch_bounds__(256, 3) void k_pass2(const float* __restrict__ Z,
                                                  const float* __restrict__ W,
                                                  const float* __restrict__ ws,
                                                  float* __restrict__ out) {
    __shared__ f16x8 Bf[2048];        // 32 KB
    __shared__ float Zs[4][16][68];   // 17.4 KB
    __shared__ unsigned int BtP[768]; // 3 KB packed coefs
    const int t = threadIdx.x;
    prep_W(W, Bf, t);
    {
        const unsigned int* src = (const unsigned int*)(ws + WS_B);
        BtP[t] = src[t];
        BtP[t + 256] = src[t + 256];
        BtP[t + 512] = src[t + 512];
    }
    __syncthreads();

    const int wv = t >> 6, l = t & 63, lr = l & 15, lh = l >> 4;

    for (int tt = 0; tt < TILES_PER_WAVE; ++tt) {
        const int tile = blockIdx.x * TILES_PER_BLOCK + wv * TILES_PER_WAVE + tt;
        const int n0 = tile * 16;
        stage_Z(Z, n0, Zs[wv], l);
        f16x8 ah0, al0, ah1, al1;
        frags_from_lds(Zs[wv], lr, lh, ah0, al0, ah1, al1);
        f32x4 acc[16];
#pragma unroll
        for (int ct = 0; ct < 16; ++ct) acc[ct] = (f32x4){0.f, 0.f, 0.f, 0.f};
#pragma unroll
        for (int ct = 0; ct < 16; ++ct) {
            f16x8 b0 = Bf[(ct * 2 + 0) * 64 + l];
            f16x8 b1 = Bf[(ct * 2 + 1) * 64 + l];
            acc[ct] = mfma16(ah0, b0, acc[ct]);
            acc[ct] = mfma16(ah1, b1, acc[ct]);
            acc[ct] = mfma16(al0, b0, acc[ct]);
            acc[ct] = mfma16(al1, b1, acc[ct]);
        }
        float pa[4][3];
#pragma unroll
        for (int r = 0; r < 4; ++r) { pa[r][0] = 0.f; pa[r][1] = 0.f; pa[r][2] = 0.f; }
#pragma unroll
        for (int ct = 0; ct < 16; ++ct) {
            const int f = ct * 16 + lr;
            unsigned int u0 = BtP[f * 3 + 0], u1 = BtP[f * 3 + 1], u2 = BtP[f * 3 + 2];
            float bc0 = __uint_as_float(u0 << 16), bs0 = __uint_as_float(u0 & 0xffff0000u);
            float bc1 = __uint_as_float(u1 << 16), bs1 = __uint_as_float(u1 & 0xffff0000u);
            float bc2 = __uint_as_float(u2 << 16), bs2 = __uint_as_float(u2 & 0xffff0000u);
#pragma unroll
            for (int r = 0; r < 4; ++r) {
                float sn, cs;
                __sincosf(acc[ct][r], &sn, &cs);
                pa[r][0] = __builtin_fmaf(cs, bc0, __builtin_fmaf(sn, bs0, pa[r][0]));
                pa[r][1] = __builtin_fmaf(cs, bc1, __builtin_fmaf(sn, bs1, pa[r][1]));
                pa[r][2] = __builtin_fmaf(cs, bc2, __builtin_fmaf(sn, bs2, pa[r][2]));
            }
        }
#pragma unroll
        for (int r = 0; r < 4; ++r)
#pragma unroll
            for (int j = 0; j < 3; ++j) {
                pa[r][j] += __shfl_xor(pa[r][j], 1);
                pa[r][j] += __shfl_xor(pa[r][j], 2);
                pa[r][j] += __shfl_xor(pa[r][j], 4);
                pa[r][j] += __shfl_xor(pa[r][j], 8);
            }
        float q0 = 0.f, q1 = 0.f, q2 = 0.f;
#pragma unroll
        for (int r = 0; r < 4; ++r)
            if (lr == r) { q0 = pa[r][0]; q1 = pa[r][1]; q2 = pa[r][2]; }
        if (lr < 4) {
            const size_t n = (size_t)n0 + 4 * lh + lr;
            out[OFF_PRED + n * 3 + 0] = q0;
            out[OFF_PRED + n * 3 + 1] = q1;
            out[OFF_PRED + n * 3 + 2] = q2;
            float x0 = q0 * 0.0625f, x1 = q1 * 0.0625f, x2 = q2 * 0.0625f;
            float m = fmaxf(x0, fmaxf(x1, x2));
            float e0 = __expf(x0 - m), e1 = __expf(x1 - m), e2 = __expf(x2 - m);
            float inv = 1.0f / (e0 + e1 + e2);
            out[OFF_AW + n * 3 + 0] = e0 * inv;
            out[OFF_AW + n * 3 + 1] = e1 * inv;
            out[OFF_AW + n * 3 + 2] = e2 * inv;
        }
    }
}

extern "C" void kernel_launch(void* const* d_in, const int* in_sizes, int n_in,
                              void* d_out, int out_size, void* d_ws, size_t ws_size,
                              hipStream_t stream) {
    const float* Z = (const float*)d_in[0];
    const float* W = (const float*)d_in[1];
    const float* A = (const float*)d_in[2];
    float* out = (float*)d_out;
    float* ws = (float*)d_ws;

    (void)hipMemsetAsync(ws, 0, 512 * sizeof(float), stream);
    hipLaunchKernelGGL(k_pass1, dim3(GRID_BIG), dim3(256), 0, stream, Z, W, ws);
    hipLaunchKernelGGL(k_alpha, dim3(1), dim3(256), 0, stream, ws, A, ws, out);
    hipLaunchKernelGGL(k_pass2, dim3(GRID_BIG), dim3(256), 0, stream, Z, W, ws, out);
}